// Round 2
// baseline (928.859 us; speedup 1.0000x reference)
//
#include <hip/hip_runtime.h>

// UniformShardedEmbeddingBags: per-table embedding bag, sum pooling.
// weights: [E=200000, T=16, D=64] fp32 (row (e,t) = 256 B contiguous, 256 B aligned)
// indices: [B=4096, T=16, L=20] int32
// out:     [B, T, D] fp32
//
// Regime (R1 evidence): random-256B-gather DRAM-bound (~1 TB/s effective), not
// issue-bound. Lever: temporal TABLE PHASING for L3 reuse capture.
//   - blockIdx.y = table t (x is the fast dispatch dim) -> the ~2048
//     co-resident blocks span only ~4 tables at any instant. Live L3
//     footprint ~= 4 tables x ~21 MB touched = ~84 MB << 256 MB L3, so the
//     ~18% within-table index re-hits (81920 draws on 200K rows) become L3
//     hits instead of HBM re-fetches: weights HBM bytes 419 MB -> ~292 MB.
//   - 32 lanes per bag: lane group g in {0,1} sums its half of the L=20 bag,
//     one __shfl_xor(16) folds the halves. Each gather instruction still
//     moves 4 x 256 B = 1 KiB (4 distinct rows per wave).
//   - 32-bit addressing: byte off = (e<<12) | (t*256 + sub*16), exact since
//     e < 2^18 and the low 12 bits of e<<12 are zero.
//   - Output stores nontemporal: 16.8 MB streamed once; don't evict weight
//     lines from L2/L3.

constexpr int E = 200000;
constexpr int T = 16;
constexpr int D = 64;
constexpr int B = 4096;
constexpr int L = 20;

constexpr int BAGS_PER_BLOCK = 8;   // 256 threads / 32 lanes per bag
constexpr int LHALF = L / 2;        // 10 gathers per lane

typedef float f32x4 __attribute__((ext_vector_type(4)));

__global__ __launch_bounds__(256) void embed_bag_kernel(
    const float* __restrict__ w,      // [E, T, D]
    const int* __restrict__ idx,      // [B, T, L]
    float* __restrict__ out)          // [B, T, D]
{
    const int t    = blockIdx.y;          // table (phased by dispatch order)
    const int tid  = threadIdx.x;
    const int bagl = tid >> 5;            // local bag 0..7
    const int g    = (tid >> 4) & 1;      // which half of the bag's L
    const int sub  = tid & 15;            // which float4 of the D=64 row
    const int b    = blockIdx.x * BAGS_PER_BLOCK + bagl;

    // This lane-group's 10 indices (contiguous 40 B, 16-lane broadcast reads).
    const int* __restrict__ slab = idx + ((size_t)b * T + t) * L + g * LHALF;

    const unsigned lane_off = (unsigned)(t * (D * 4) + sub * 16);
    const char* __restrict__ wb = (const char*)w;

    // 10 independent 1 KiB/wave gathers.
    f32x4 acc = {0.f, 0.f, 0.f, 0.f};
#pragma unroll
    for (int k = 0; k < LHALF; ++k) {
        const unsigned off = ((unsigned)slab[k] << 12) | lane_off;
        const f32x4 v = *(const f32x4*)(wb + off);
        acc += v;
    }

    // Fold the two L-halves: partner lane differs in bit 4 (same bag).
    acc.x += __shfl_xor(acc.x, 16);
    acc.y += __shfl_xor(acc.y, 16);
    acc.z += __shfl_xor(acc.z, 16);
    acc.w += __shfl_xor(acc.w, 16);

    if (g == 0) {
        f32x4* dst = (f32x4*)(out + ((size_t)b * T + t) * D + sub * 4);
        __builtin_nontemporal_store(acc, dst);
    }
}

extern "C" void kernel_launch(void* const* d_in, const int* in_sizes, int n_in,
                              void* d_out, int out_size, void* d_ws, size_t ws_size,
                              hipStream_t stream) {
    const float* w  = (const float*)d_in[0];
    const int* idx  = (const int*)d_in[1];
    float* out      = (float*)d_out;

    // grid.x fast dim = 512 b-chunks, grid.y = 16 tables (phased).
    embed_bag_kernel<<<dim3(B / BAGS_PER_BLOCK, T), 256, 0, stream>>>(w, idx, out);
}